// Round 6
// baseline (592.668 us; speedup 1.0000x reference)
//
#include <hip/hip_runtime.h>
#include <cstdint>
#include <cstddef>

typedef __bf16 bf16;
typedef __bf16 bf16x8 __attribute__((ext_vector_type(8)));
typedef float  f32x4  __attribute__((ext_vector_type(4)));

static_assert(sizeof(bf16x8) == 16, "bf16x8 must be 16B");

// async global->LDS, 16B per lane; lane i's data lands at ldsbase + i*16.
__device__ __forceinline__ void async_copy16(const bf16* g, bf16* l) {
  __builtin_amdgcn_global_load_lds(
      (__attribute__((address_space(1))) void*)(g),
      (__attribute__((address_space(3))) void*)(l),
      16, 0, 0);
}

// fp32 -> bf16 bulk convert, 8 elems/thread. n must be a multiple of 2048.
__global__ __launch_bounds__(256)
void conv_f32_bf16(const float* __restrict__ s, bf16* __restrict__ d) {
  const size_t i = ((size_t)blockIdx.x * 256 + threadIdx.x) * 8;
  const f32x4 a = *(const f32x4*)(s + i);
  const f32x4 b = *(const f32x4*)(s + i + 4);
  bf16x8 o;
#pragma unroll
  for (int e = 0; e < 4; ++e) { o[e] = (bf16)a[e]; o[4 + e] = (bf16)b[e]; }
  *(bf16x8*)(d + i) = o;
}

// C[m,n] = sum_k A[m,k] * W[n,k], all-bf16 m97-style: 128x128 tile, BK=64,
// async global->LDS both operands, XOR chunk swizzle (LDS[row][c]=G[row][c^(row&7)]).
// AMODE 0: A row-major [M,K].  AMODE 2: A gathered from [B,H,S,D] plane (k=h*128+d).
// CMODE 0: C fp32 row-major -> Crow.
// CMODE 1: C scattered bf16; global col = nbase+n: <2048 -> Cq[b,h,s,d],
//          <4096 -> Ck[b,h,s,d], else -> Cvt TRANSPOSED [b,h,d,s].
template<int AMODE, int CMODE>
__global__ __launch_bounds__(256, 2)
void gemm_bt(const bf16* __restrict__ A, const bf16* __restrict__ W,
             float* __restrict__ Crow, bf16* __restrict__ Cq,
             bf16* __restrict__ Ck, bf16* __restrict__ Cvt,
             int M, int N, int K, int nbase) {
  __shared__ bf16 As[128 * 64];
  __shared__ bf16 Ws[128 * 64];

  const int tid  = threadIdx.x;
  const int wave = tid >> 6;
  const int lane = tid & 63;
  const int quad = lane >> 4;
  const int r    = lane & 15;
  const int m0 = blockIdx.y * 128;
  const int n0 = blockIdx.x * 128;
  const int wm = (wave >> 1) * 64;
  const int wn = (wave & 1) * 64;

  const int lrow   = lane >> 3;      // 0..7
  const int gchunk = (lane & 7) ^ lrow;

  f32x4 acc[4][4] = {};

  for (int k0 = 0; k0 < K; k0 += 64) {
    __syncthreads();
    for (int j = 0; j < 4; ++j) {
      const int rbase = (wave * 4 + j) * 8;
      const int rowA  = m0 + rbase + lrow;
      const bf16* aSrc;
      if constexpr (AMODE == 2) {
        const int b = rowA >> 11, s = rowA & 2047;
        aSrc = A + ((size_t)(b * 16 + (k0 >> 7)) * 2048 + s) * 128
                 + (k0 & 127) + gchunk * 8;
      } else {
        aSrc = A + (size_t)rowA * K + k0 + gchunk * 8;
      }
      async_copy16(aSrc, As + rbase * 64);
      async_copy16(W + (size_t)(n0 + rbase + lrow) * K + k0 + gchunk * 8,
                   Ws + rbase * 64);
    }
    __syncthreads();
    for (int ks = 0; ks < 2; ++ks) {
      bf16x8 af[4], bfv[4];
      for (int i = 0; i < 4; ++i) {
        const int ar = wm + i * 16 + r;
        af[i]  = *(const bf16x8*)(As + ar * 64 + (((ks * 4 + quad) ^ (ar & 7)) * 8));
        const int br = wn + i * 16 + r;
        bfv[i] = *(const bf16x8*)(Ws + br * 64 + (((ks * 4 + quad) ^ (br & 7)) * 8));
      }
      for (int i = 0; i < 4; ++i)
        for (int j = 0; j < 4; ++j)
          acc[i][j] = __builtin_amdgcn_mfma_f32_16x16x32_bf16(af[i], bfv[j], acc[i][j], 0, 0, 0);
    }
  }

  // C-layout: row = quad*4+reg, col = lane&15 (m89-verified).
  for (int i = 0; i < 4; ++i) {
    const int growb = m0 + wm + i * 16 + quad * 4;
    for (int j = 0; j < 4; ++j) {
      const int gcol = n0 + wn + j * 16 + r;
      for (int rg = 0; rg < 4; ++rg) {
        const int grow = growb + rg;
        if constexpr (CMODE == 1) {
          const int gc = nbase + gcol;
          const int which = gc >> 11;
          const int h = (gc >> 7) & 15;
          const int d = gc & 127;
          const int b = grow >> 11;
          const int s = grow & 2047;
          const bf16 v = (bf16)acc[i][j][rg];
          if (which == 0)
            Cq[(((size_t)b * 16 + h) * 2048 + s) * 128 + d] = v;
          else if (which == 1)
            Ck[(((size_t)b * 16 + h) * 2048 + s) * 128 + d] = v;
          else
            Cvt[(((size_t)b * 16 + h) * 128 + d) * 2048 + s] = v;  // transposed
        } else {
          Crow[(size_t)grow * N + gcol] = acc[i][j][rg];
        }
      }
    }
  }
}

// Flash attention, causal. Q,K: [B*H, S, 128] bf16; Vt: [B*H, 128, S] bf16
// (pre-transposed). O written IN-PLACE into the Q plane (block-private rows).
// Q-tile 64 rows/block, wave w owns rows q0+w*16 (one MFMA m-tile) ->
// grid (S/64, B*H) = 1024 blocks; LDS 40KB -> 4 blocks/CU, 16 waves/CU.
// qb REVERSED so heavy diagonal blocks dispatch first.
// All LDS XOR-swizzled on 8-elem chunks: LDS[row][c] holds G[row][c^(row&7)].
__global__ __launch_bounds__(256, 4)
void attn_kernel(bf16* __restrict__ Q, const bf16* __restrict__ K,
                 const bf16* __restrict__ Vt, int S) {
  __shared__ bf16 k_lds[64 * 128];   // [kv][d], swizzled
  __shared__ bf16 v_lds[128 * 64];   // [d][kv], swizzled
  __shared__ bf16 p_lds[4][16 * 64]; // per-wave P [qrow][kv], swizzled

  const int tid = threadIdx.x, wave = tid >> 6, lane = tid & 63;
  const int quad = lane >> 4, r = lane & 15;
  const int bh = blockIdx.y;
  const int q0 = (gridDim.x - 1 - blockIdx.x) * 64;  // reversed for balance
  const int qrow0 = q0 + wave * 16;
  bf16* Qh = Q + (size_t)bh * S * 128;
  const bf16* Kh = K + (size_t)bh * S * 128;
  const bf16* Vth = Vt + (size_t)bh * 128 * S;

  // Q fragments in registers: A[m=lane&15][k=quad*8+j] per 32-k step
  bf16x8 qf[4];
  for (int ks = 0; ks < 4; ++ks)
    qf[ks] = *(const bf16x8*)(Qh + (size_t)(qrow0 + r) * 128 + ks * 32 + quad * 8);

  f32x4 o_acc[8] = {};
  f32x4 m_run, l_run;
  for (int t = 0; t < 4; ++t) { m_run[t] = -1e30f; l_run[t] = 0.f; }

  const float sc = 0.0883883476483184f * 1.4426950408889634f; // 1/sqrt(128)*log2e
  const int nkv = (q0 + 64) >> 6;

  for (int kt = 0; kt < nkv; ++kt) {
    const int kv0 = kt << 6;
    __syncthreads();
    // stage K [64 kv][16 chunks of 8 d], swizzled
    for (int j = 0; j < 4; ++j) {
      const int lin = j * 256 + tid;
      const int row = lin >> 4;
      const int ch  = lin & 15;
      *(bf16x8*)(k_lds + row * 128 + (ch ^ (row & 7)) * 8) =
          *(const bf16x8*)(Kh + (size_t)(kv0 + row) * 128 + ch * 8);
    }
    // stage V^T [128 d][8 chunks of 8 kv], swizzled — vectorized both sides
    for (int j = 0; j < 4; ++j) {
      const int lin = j * 256 + tid;
      const int row = lin >> 3;   // d
      const int c   = lin & 7;    // kv chunk
      *(bf16x8*)(v_lds + row * 64 + (c ^ (row & 7)) * 8) =
          *(const bf16x8*)(Vth + (size_t)row * S + kv0 + c * 8);
    }
    __syncthreads();

    // S = Q K^T  (one 16-row m-tile per wave)
    f32x4 sa[4] = {};
    for (int ks = 0; ks < 4; ++ks) {
      bf16x8 kf[4];
      for (int nt = 0; nt < 4; ++nt) {
        const int kr = nt * 16 + r;
        kf[nt] = *(const bf16x8*)(k_lds + kr * 128 + (((ks * 4 + quad) ^ (kr & 7)) * 8));
      }
      for (int nt = 0; nt < 4; ++nt)
        sa[nt] = __builtin_amdgcn_mfma_f32_16x16x32_bf16(qf[ks], kf[nt], sa[nt], 0, 0, 0);
    }
    // causal mask on the diagonal tile
    if (kv0 + 63 > qrow0) {
      for (int nt = 0; nt < 4; ++nt) {
        const int col  = kv0 + nt * 16 + r;
        const int rowb = qrow0 + quad * 4;
        for (int rg = 0; rg < 4; ++rg)
          if (col > rowb + rg) sa[nt][rg] = -1e30f;
      }
    }
    // online softmax (each score row lives on the 16 lanes of one quad)
    {
      f32x4 mx = sa[0];
      for (int nt = 1; nt < 4; ++nt)
        for (int rg = 0; rg < 4; ++rg) mx[rg] = fmaxf(mx[rg], sa[nt][rg]);
      for (int off = 1; off < 16; off <<= 1)
        for (int rg = 0; rg < 4; ++rg) mx[rg] = fmaxf(mx[rg], __shfl_xor(mx[rg], off, 64));
      f32x4 alpha;
      for (int rg = 0; rg < 4; ++rg) {
        const float mnew = fmaxf(m_run[rg], mx[rg]);
        alpha[rg] = exp2f((m_run[rg] - mnew) * sc);
        m_run[rg] = mnew;
      }
      f32x4 rsum = {0.f, 0.f, 0.f, 0.f};
      for (int nt = 0; nt < 4; ++nt)
        for (int rg = 0; rg < 4; ++rg) {
          const float p = exp2f((sa[nt][rg] - m_run[rg]) * sc);
          sa[nt][rg] = p;
          rsum[rg] += p;
        }
      for (int off = 1; off < 16; off <<= 1)
        for (int rg = 0; rg < 4; ++rg) rsum[rg] += __shfl_xor(rsum[rg], off, 64);
      for (int rg = 0; rg < 4; ++rg) l_run[rg] = l_run[rg] * alpha[rg] + rsum[rg];
      for (int nt2 = 0; nt2 < 8; ++nt2)
        for (int rg = 0; rg < 4; ++rg) o_acc[nt2][rg] *= alpha[rg];
      // P: C-layout -> A-layout via per-wave LDS round-trip, swizzled
      for (int nt = 0; nt < 4; ++nt)
        for (int rg = 0; rg < 4; ++rg) {
          const int prow = quad * 4 + rg;
          const int pcol = nt * 16 + r;
          p_lds[wave][prow * 64 + (((pcol >> 3) ^ (prow & 7)) * 8) + (pcol & 7)] =
              (bf16)sa[nt][rg];
        }
    }
    // O += P V
    for (int ks2 = 0; ks2 < 2; ++ks2) {
      const bf16x8 pf = *(const bf16x8*)(p_lds[wave] + r * 64 + (((ks2 * 4 + quad) ^ (r & 7)) * 8));
      for (int nt2 = 0; nt2 < 8; ++nt2) {
        const int vrow = nt2 * 16 + r;
        const bf16x8 vf = *(const bf16x8*)(v_lds + vrow * 64 + (((ks2 * 4 + quad) ^ (vrow & 7)) * 8));
        o_acc[nt2] = __builtin_amdgcn_mfma_f32_16x16x32_bf16(pf, vf, o_acc[nt2], 0, 0, 0);
      }
    }
  }

  // epilogue: write O back into the Q plane, same [b,h,s,d] coords
  f32x4 inv;
  for (int rg = 0; rg < 4; ++rg) inv[rg] = 1.0f / l_run[rg];
  for (int nt2 = 0; nt2 < 8; ++nt2) {
    const int d = nt2 * 16 + r;
    for (int rg = 0; rg < 4; ++rg) {
      const int s = qrow0 + quad * 4 + rg;
      Qh[(size_t)s * 128 + d] = (bf16)(o_acc[nt2][rg] * inv[rg]);
    }
  }
}

extern "C" void kernel_launch(void* const* d_in, const int* in_sizes, int n_in,
                              void* d_out, int out_size, void* d_ws, size_t ws_size,
                              hipStream_t stream) {
  const float* x     = (const float*)d_in[0];   // [2,2048,2048] fp32
  const float* Wqkv  = (const float*)d_in[1];   // [6144,2048] fp32
  const float* Wproj = (const float*)d_in[2];   // [2048,2048] fp32
  float* out = (float*)d_out;                   // [2,2048,2048] fp32 = 32 MiB

  const int Bm = 4096, E = 2048;
  const size_t plane = 8388608;                 // 16 MiB as bf16

  // ws (48 MiB): [0,plane) Q plane; [plane,2p) V^T plane; [2p,3p) xb then Wproj_bf16.
  // d_out (32 MiB): [0,plane) bf16 K plane; [plane,+6291456) bf16 Wqkv half;
  //   both dead before proj GEMM overwrites d_out with fp32 output.
  bf16* qw  = (bf16*)d_ws;
  bf16* vtw = qw + plane;
  bf16* xb  = vtw + plane;       // later reused for Wproj bf16
  bf16* kw  = (bf16*)d_out;
  bf16* wqb = kw + plane;        // 6291456 elems = 12 MiB, fits in d_out upper half

  // 1) x -> bf16
  conv_f32_bf16<<<8388608 / 2048, 256, 0, stream>>>(x, xb);
  // 2) Wqkv rows [0,3072) -> bf16
  conv_f32_bf16<<<6291456 / 2048, 256, 0, stream>>>(Wqkv, wqb);
  // 3) QKV GEMM chunk A: n in [0,3072) -> all Q + K heads 0..7
  gemm_bt<0, 1><<<dim3(3072 / 128, Bm / 128), 256, 0, stream>>>(
      xb, wqb, nullptr, qw, kw, vtw, Bm, 3072, E, 0);
  // 4) Wqkv rows [3072,6144) -> bf16 (overwrites wqb after chunk A)
  conv_f32_bf16<<<6291456 / 2048, 256, 0, stream>>>(Wqkv + 6291456, wqb);
  // 5) QKV GEMM chunk B: n in [3072,6144) -> K heads 8..15 + all V (transposed)
  gemm_bt<0, 1><<<dim3(3072 / 128, Bm / 128), 256, 0, stream>>>(
      xb, wqb, nullptr, qw, kw, vtw, Bm, 3072, E, 3072);
  // 6) attention (O overwrites Q plane), q-tile 64
  attn_kernel<<<dim3(2048 / 64, 32), 256, 0, stream>>>(qw, kw, vtw, 2048);
  // 7) Wproj -> bf16 (xb region; xb dead)
  conv_f32_bf16<<<4194304 / 2048, 256, 0, stream>>>(Wproj, xb);
  // 8) proj GEMM: A = O plane (gather), C = d_out fp32
  gemm_bt<2, 0><<<dim3(2048 / 128, Bm / 128), 256, 0, stream>>>(
      qw, xb, out, nullptr, nullptr, nullptr, Bm, 2048, E, 0);
}

// Round 7
// 452.075 us; speedup vs baseline: 1.3110x; 1.3110x over previous
//
#include <hip/hip_runtime.h>
#include <cstdint>
#include <cstddef>

typedef __bf16 bf16;
typedef __bf16 bf16x8 __attribute__((ext_vector_type(8)));
typedef float  f32x4  __attribute__((ext_vector_type(4)));

static_assert(sizeof(bf16x8) == 16, "bf16x8 must be 16B");

// async global->LDS, 16B per lane; lane i's data lands at ldsbase + i*16.
__device__ __forceinline__ void async_copy16(const bf16* g, bf16* l) {
  __builtin_amdgcn_global_load_lds(
      (__attribute__((address_space(1))) void*)(g),
      (__attribute__((address_space(3))) void*)(l),
      16, 0, 0);
}

// fp32 -> bf16 bulk convert, 8 elems/thread. n must be a multiple of 2048.
__global__ __launch_bounds__(256)
void conv_f32_bf16(const float* __restrict__ s, bf16* __restrict__ d) {
  const size_t i = ((size_t)blockIdx.x * 256 + threadIdx.x) * 8;
  const f32x4 a = *(const f32x4*)(s + i);
  const f32x4 b = *(const f32x4*)(s + i + 4);
  bf16x8 o;
#pragma unroll
  for (int e = 0; e < 4; ++e) { o[e] = (bf16)a[e]; o[4 + e] = (bf16)b[e]; }
  *(bf16x8*)(d + i) = o;
}

// C[m,n] = sum_k A[m,k] * W[n,k], all-bf16 m97-style: 128x128 tile, BK=64,
// async global->LDS both operands, XOR chunk swizzle (LDS[row][c]=G[row][c^(row&7)]).
// AMODE 0: A row-major [M,K].  AMODE 2: A gathered from [B,H,S,D] plane (k=h*128+d).
// CMODE 0: C fp32 row-major -> Crow.
// CMODE 1: C scattered bf16; global col = nbase+n: <2048 -> Cq[b,h,s,d],
//          <4096 -> Ck[b,h,s,d], else -> Cvt TRANSPOSED [b,h,d,s].
template<int AMODE, int CMODE>
__global__ __launch_bounds__(256, 2)
void gemm_bt(const bf16* __restrict__ A, const bf16* __restrict__ W,
             float* __restrict__ Crow, bf16* __restrict__ Cq,
             bf16* __restrict__ Ck, bf16* __restrict__ Cvt,
             int M, int N, int K, int nbase) {
  __shared__ bf16 As[128 * 64];
  __shared__ bf16 Ws[128 * 64];

  const int tid  = threadIdx.x;
  const int wave = tid >> 6;
  const int lane = tid & 63;
  const int quad = lane >> 4;
  const int r    = lane & 15;
  const int m0 = blockIdx.y * 128;
  const int n0 = blockIdx.x * 128;
  const int wm = (wave >> 1) * 64;
  const int wn = (wave & 1) * 64;

  const int lrow   = lane >> 3;      // 0..7
  const int gchunk = (lane & 7) ^ lrow;

  f32x4 acc[4][4] = {};

  for (int k0 = 0; k0 < K; k0 += 64) {
    __syncthreads();
    for (int j = 0; j < 4; ++j) {
      const int rbase = (wave * 4 + j) * 8;
      const int rowA  = m0 + rbase + lrow;
      const bf16* aSrc;
      if constexpr (AMODE == 2) {
        const int b = rowA >> 11, s = rowA & 2047;
        aSrc = A + ((size_t)(b * 16 + (k0 >> 7)) * 2048 + s) * 128
                 + (k0 & 127) + gchunk * 8;
      } else {
        aSrc = A + (size_t)rowA * K + k0 + gchunk * 8;
      }
      async_copy16(aSrc, As + rbase * 64);
      async_copy16(W + (size_t)(n0 + rbase + lrow) * K + k0 + gchunk * 8,
                   Ws + rbase * 64);
    }
    __syncthreads();
    for (int ks = 0; ks < 2; ++ks) {
      bf16x8 af[4], bfv[4];
      for (int i = 0; i < 4; ++i) {
        const int ar = wm + i * 16 + r;
        af[i]  = *(const bf16x8*)(As + ar * 64 + (((ks * 4 + quad) ^ (ar & 7)) * 8));
        const int br = wn + i * 16 + r;
        bfv[i] = *(const bf16x8*)(Ws + br * 64 + (((ks * 4 + quad) ^ (br & 7)) * 8));
      }
      for (int i = 0; i < 4; ++i)
        for (int j = 0; j < 4; ++j)
          acc[i][j] = __builtin_amdgcn_mfma_f32_16x16x32_bf16(af[i], bfv[j], acc[i][j], 0, 0, 0);
    }
  }

  // C-layout: row = quad*4+reg, col = lane&15 (m89-verified).
  for (int i = 0; i < 4; ++i) {
    const int growb = m0 + wm + i * 16 + quad * 4;
    for (int j = 0; j < 4; ++j) {
      const int gcol = n0 + wn + j * 16 + r;
      for (int rg = 0; rg < 4; ++rg) {
        const int grow = growb + rg;
        if constexpr (CMODE == 1) {
          const int gc = nbase + gcol;
          const int which = gc >> 11;
          const int h = (gc >> 7) & 15;
          const int d = gc & 127;
          const int b = grow >> 11;
          const int s = grow & 2047;
          const bf16 v = (bf16)acc[i][j][rg];
          if (which == 0)
            Cq[(((size_t)b * 16 + h) * 2048 + s) * 128 + d] = v;
          else if (which == 1)
            Ck[(((size_t)b * 16 + h) * 2048 + s) * 128 + d] = v;
          else
            Cvt[(((size_t)b * 16 + h) * 128 + d) * 2048 + s] = v;  // transposed
        } else {
          Crow[(size_t)grow * N + gcol] = acc[i][j][rg];
        }
      }
    }
  }
}

// Flash attention, causal. Q,K: [B*H, S, 128] bf16; Vt: [B*H, 128, S] bf16
// (pre-transposed). O written IN-PLACE into the Q plane (block-private rows).
// Q-tile 128/block (wave w owns rows q0+w*32..+32). Grid (S/128, B*H), qb
// reversed so heavy diagonal blocks dispatch first.
// KV staged via async global_load_lds into DOUBLE-BUFFERED LDS with ONE
// barrier per tile: loads for tile t+1 fly during compute of tile t.
// XOR swizzle is applied to the GLOBAL source address (deposit order is
// fixed), so LDS[row][c] = G[row][c^(row&7)] within each 8-chunk panel;
// fragment reads land <=2-way on banks (free, m136).
__global__ __launch_bounds__(256, 2)
void attn_kernel(bf16* __restrict__ Q, const bf16* __restrict__ K,
                 const bf16* __restrict__ Vt, int S) {
  __shared__ bf16 k_lds[2 * 2 * 64 * 64];  // [buf][dhalf][kv][64], 32 KB
  __shared__ bf16 v_lds[2 * 128 * 64];     // [buf][d][kv-chunked 64], 32 KB
  __shared__ bf16 p_lds[4 * 32 * 64];      // per-wave P [qrow][kv], 16 KB

  const int tid = threadIdx.x, wave = tid >> 6, lane = tid & 63;
  const int quad = lane >> 4, r = lane & 15;
  const int lrow = lane >> 3;              // 0..7 within a staging issue
  const int gchunk = (lane & 7) ^ lrow;    // global-side XOR swizzle
  const int bh = blockIdx.y;
  const int q0 = (gridDim.x - 1 - blockIdx.x) * 128;  // reversed for balance
  const int qrow0 = q0 + wave * 32;
  bf16* Qh = Q + (size_t)bh * S * 128;
  const bf16* Kh = K + (size_t)bh * S * 128;
  const bf16* Vth = Vt + (size_t)bh * 128 * S;

  // Q fragments in registers: A[m=lane&15][k=quad*8+j] per 32-k step
  bf16x8 qf[2][4];
  for (int mt = 0; mt < 2; ++mt)
    for (int ks = 0; ks < 4; ++ks)
      qf[mt][ks] = *(const bf16x8*)(Qh + (size_t)(qrow0 + mt * 16 + r) * 128 + ks * 32 + quad * 8);

  f32x4 o_acc[2][8] = {};
  f32x4 m_run[2], l_run[2];
  for (int mt = 0; mt < 2; ++mt)
    for (int t = 0; t < 4; ++t) { m_run[mt][t] = -1e30f; l_run[mt][t] = 0.f; }

  const float sc = 0.0883883476483184f * 1.4426950408889634f; // 1/sqrt(128)*log2e
  const int nkv = (q0 + 128) >> 6;

  // stage one 64-kv tile into buffer `buf` (8 async issues per wave)
  auto stage_tile = [&](int kv0, int buf) {
#pragma unroll
    for (int t = 0; t < 4; ++t) {
      // K: issue id covers rows rg*8..+8 of d-half `half`
      const int id = wave * 4 + t;
      const int rg = id >> 1, half = id & 1;
      async_copy16(Kh + (size_t)(kv0 + rg * 8 + lrow) * 128 + half * 64 + gchunk * 8,
                   k_lds + buf * 8192 + half * 4096 + rg * 512);
      // V^T: issue id covers d rows rgv*8..+8 (64 kv elems each)
      const int rgv = wave * 4 + t;
      async_copy16(Vth + (size_t)(rgv * 8 + lrow) * S + kv0 + gchunk * 8,
                   v_lds + buf * 8192 + rgv * 512);
    }
  };

  stage_tile(0, 0);

  for (int kt = 0; kt < nkv; ++kt) {
    const int kv0 = kt << 6;
    __syncthreads();                 // retires buf[kt&1] loads (vmcnt drain)
    if (kt + 1 < nkv) stage_tile((kt + 1) << 6, (kt + 1) & 1);
    const int bo = (kt & 1) * 8192;

    if (kv0 <= qrow0 + 31) {  // tile not fully masked for this wave
      // S = Q K^T
      f32x4 sa[2][4] = {};
      for (int ks = 0; ks < 4; ++ks) {
        const int idx = ks * 4 + quad;          // d-chunk 0..15
        const int half = idx >> 3, cg = idx & 7;
        bf16x8 kf[4];
        for (int nt = 0; nt < 4; ++nt) {
          const int kr = nt * 16 + r;
          kf[nt] = *(const bf16x8*)(k_lds + bo + half * 4096 + kr * 64 + ((cg ^ (r & 7)) * 8));
        }
        for (int mt = 0; mt < 2; ++mt)
          for (int nt = 0; nt < 4; ++nt)
            sa[mt][nt] = __builtin_amdgcn_mfma_f32_16x16x32_bf16(qf[mt][ks], kf[nt], sa[mt][nt], 0, 0, 0);
      }
      // causal mask on diagonal tiles
      if (kv0 + 63 > qrow0) {
        for (int mt = 0; mt < 2; ++mt)
          for (int nt = 0; nt < 4; ++nt) {
            const int col  = kv0 + nt * 16 + r;
            const int rowb = qrow0 + mt * 16 + quad * 4;
            for (int rg = 0; rg < 4; ++rg)
              if (col > rowb + rg) sa[mt][nt][rg] = -1e30f;
          }
      }
      // online softmax (each score row lives on the 16 lanes of one quad)
      for (int mt = 0; mt < 2; ++mt) {
        f32x4 mx = sa[mt][0];
        for (int nt = 1; nt < 4; ++nt)
          for (int rg = 0; rg < 4; ++rg) mx[rg] = fmaxf(mx[rg], sa[mt][nt][rg]);
        for (int off = 1; off < 16; off <<= 1)
          for (int rg = 0; rg < 4; ++rg) mx[rg] = fmaxf(mx[rg], __shfl_xor(mx[rg], off, 64));
        f32x4 alpha;
        for (int rg = 0; rg < 4; ++rg) {
          const float mnew = fmaxf(m_run[mt][rg], mx[rg]);
          alpha[rg] = exp2f((m_run[mt][rg] - mnew) * sc);
          m_run[mt][rg] = mnew;
        }
        f32x4 rsum = {0.f, 0.f, 0.f, 0.f};
        for (int nt = 0; nt < 4; ++nt)
          for (int rg = 0; rg < 4; ++rg) {
            const float p = exp2f((sa[mt][nt][rg] - m_run[mt][rg]) * sc);
            sa[mt][nt][rg] = p;
            rsum[rg] += p;
          }
        for (int off = 1; off < 16; off <<= 1)
          for (int rg = 0; rg < 4; ++rg) rsum[rg] += __shfl_xor(rsum[rg], off, 64);
        for (int rg = 0; rg < 4; ++rg) l_run[mt][rg] = l_run[mt][rg] * alpha[rg] + rsum[rg];
        for (int nt2 = 0; nt2 < 8; ++nt2)
          for (int rg = 0; rg < 4; ++rg) o_acc[mt][nt2][rg] *= alpha[rg];
        // P: C-layout -> A-layout via per-wave LDS round-trip.
        // swizzle = (chunk) ^ (prow&7) ^ ((prow>>3)&1): all 4 quads land on
        // distinct chunk slots -> <=2-way banks on the scalar writes.
        for (int nt = 0; nt < 4; ++nt)
          for (int rg = 0; rg < 4; ++rg) {
            const int prow = mt * 16 + quad * 4 + rg;
            const int pcol = nt * 16 + r;
            const int swz = ((pcol >> 3) ^ (prow & 7) ^ ((prow >> 3) & 1));
            p_lds[wave * 2048 + prow * 64 + swz * 8 + (pcol & 7)] = (bf16)sa[mt][nt][rg];
          }
      }
      // O += P V
      for (int ks2 = 0; ks2 < 2; ++ks2) {
        const int cc = ks2 * 4 + quad;          // kv-chunk 0..7
        bf16x8 pf[2];
        for (int mt = 0; mt < 2; ++mt) {
          const int prow = mt * 16 + r;
          const int swz = (cc ^ (prow & 7) ^ ((prow >> 3) & 1));
          pf[mt] = *(const bf16x8*)(p_lds + wave * 2048 + prow * 64 + swz * 8);
        }
        for (int nt2 = 0; nt2 < 8; ++nt2) {
          const int vrow = nt2 * 16 + r;
          const bf16x8 vf = *(const bf16x8*)(v_lds + bo + vrow * 64 + ((cc ^ (r & 7)) * 8));
          for (int mt = 0; mt < 2; ++mt)
            o_acc[mt][nt2] = __builtin_amdgcn_mfma_f32_16x16x32_bf16(pf[mt], vf, o_acc[mt][nt2], 0, 0, 0);
        }
      }
    }
  }

  // epilogue: write O back into the Q plane, same [b,h,s,d] coords
  for (int mt = 0; mt < 2; ++mt) {
    f32x4 inv;
    for (int rg = 0; rg < 4; ++rg) inv[rg] = 1.0f / l_run[mt][rg];
    for (int nt2 = 0; nt2 < 8; ++nt2) {
      const int d = nt2 * 16 + r;
      for (int rg = 0; rg < 4; ++rg) {
        const int s = qrow0 + mt * 16 + quad * 4 + rg;
        Qh[(size_t)s * 128 + d] = (bf16)(o_acc[mt][nt2][rg] * inv[rg]);
      }
    }
  }
}

extern "C" void kernel_launch(void* const* d_in, const int* in_sizes, int n_in,
                              void* d_out, int out_size, void* d_ws, size_t ws_size,
                              hipStream_t stream) {
  const float* x     = (const float*)d_in[0];   // [2,2048,2048] fp32
  const float* Wqkv  = (const float*)d_in[1];   // [6144,2048] fp32
  const float* Wproj = (const float*)d_in[2];   // [2048,2048] fp32
  float* out = (float*)d_out;                   // [2,2048,2048] fp32 = 32 MiB

  const int Bm = 4096, E = 2048;
  const size_t plane = 8388608;                 // 16 MiB as bf16

  // ws (48 MiB): [0,plane) Q plane; [plane,2p) V^T plane; [2p,3p) xb then Wproj_bf16.
  // d_out (32 MiB): [0,plane) bf16 K plane; [plane,+6291456) bf16 Wqkv half;
  //   both dead before proj GEMM overwrites d_out with fp32 output.
  bf16* qw  = (bf16*)d_ws;
  bf16* vtw = qw + plane;
  bf16* xb  = vtw + plane;       // later reused for Wproj bf16
  bf16* kw  = (bf16*)d_out;
  bf16* wqb = kw + plane;        // 6291456 elems = 12 MiB, fits in d_out upper half

  // 1) x -> bf16
  conv_f32_bf16<<<8388608 / 2048, 256, 0, stream>>>(x, xb);
  // 2) Wqkv rows [0,3072) -> bf16
  conv_f32_bf16<<<6291456 / 2048, 256, 0, stream>>>(Wqkv, wqb);
  // 3) QKV GEMM chunk A: n in [0,3072) -> all Q + K heads 0..7
  gemm_bt<0, 1><<<dim3(3072 / 128, Bm / 128), 256, 0, stream>>>(
      xb, wqb, nullptr, qw, kw, vtw, Bm, 3072, E, 0);
  // 4) Wqkv rows [3072,6144) -> bf16 (overwrites wqb after chunk A)
  conv_f32_bf16<<<6291456 / 2048, 256, 0, stream>>>(Wqkv + 6291456, wqb);
  // 5) QKV GEMM chunk B: n in [3072,6144) -> K heads 8..15 + all V (transposed)
  gemm_bt<0, 1><<<dim3(3072 / 128, Bm / 128), 256, 0, stream>>>(
      xb, wqb, nullptr, qw, kw, vtw, Bm, 3072, E, 3072);
  // 6) attention (O overwrites Q plane), q-tile 128, async dbuf KV pipeline
  attn_kernel<<<dim3(2048 / 128, 32), 256, 0, stream>>>(qw, kw, vtw, 2048);
  // 7) Wproj -> bf16 (xb region; xb dead)
  conv_f32_bf16<<<4194304 / 2048, 256, 0, stream>>>(Wproj, xb);
  // 8) proj GEMM: A = O plane (gather), C = d_out fp32
  gemm_bt<2, 0><<<dim3(2048 / 128, Bm / 128), 256, 0, stream>>>(
      qw, xb, out, nullptr, nullptr, nullptr, Bm, 2048, E, 0);
}